// Round 1
// baseline (2595.057 us; speedup 1.0000x reference)
//
#include <hip/hip_runtime.h>
#include <math.h>

// Problem constants (fixed by reference)
#define BQ     1024
#define D      256
#define NTRAIN 200000
#define CCLS   1000
#define KTOP   20
#define TEMPF  20.0f
#define EPSV   1e-8f

// Tiling
#define NSEG          48            // segments over train set (grid = 16*48 = 768 = 3 blocks/CU)
#define TILES_PER_SEG 66
#define SEGN          (TILES_PER_SEG * 64)   // 4224; 48*4224 = 202752 >= 200000
#define LSTR          68            // padded LDS row stride (floats): 68*4B = 272 = 17*16B (b128-aligned, conflict-free)

// ---------------------------------------------------------------------------
// Kernel 1: q = l2_normalize((x - mean) * inv_std)   [1024 x 256]
// ---------------------------------------------------------------------------
__global__ void prep_q(const float* __restrict__ x, const float* __restrict__ mean,
                       const float* __restrict__ inv_std, float* __restrict__ q) {
  int row = blockIdx.x;
  int t = threadIdx.x;                     // 256 threads, one element each
  float v = (x[row * D + t] - mean[t]) * inv_std[t];
  float s = v * v;
  #pragma unroll
  for (int off = 32; off; off >>= 1) s += __shfl_down(s, off);
  __shared__ float red[4];
  if ((t & 63) == 0) red[t >> 6] = s;
  __syncthreads();
  float tot = red[0] + red[1] + red[2] + red[3];
  float scale = 1.0f / fmaxf(sqrtf(tot), EPSV);
  q[row * D + t] = v * scale;
}

// ---------------------------------------------------------------------------
// Kernel 2: rnorm[n] = 1 / max(||train_x[n]||, eps)
// one wave per row; lane loads float4 (64*16B = 256 floats)
// ---------------------------------------------------------------------------
__global__ void row_norms(const float* __restrict__ tx, float* __restrict__ rnorm) {
  int lane = threadIdx.x & 63;
  int row = blockIdx.x * 4 + (threadIdx.x >> 6);   // grid = 50000 -> rows 0..199999 exactly
  const float4* p = reinterpret_cast<const float4*>(tx + (size_t)row * D);
  float4 a = p[lane];
  float s = a.x * a.x + a.y * a.y + a.z * a.z + a.w * a.w;
  #pragma unroll
  for (int off = 32; off; off >>= 1) s += __shfl_down(s, off);
  if (lane == 0) rnorm[row] = 1.0f / fmaxf(sqrtf(s), EPSV);
}

// ---------------------------------------------------------------------------
// Kernel 3: fused sim GEMM (fp32) + per-segment top-20
// block = 256 thr; 64 queries x SEGN train rows; 64x64 tiles, 4x4 micro-tile
// ---------------------------------------------------------------------------
__global__ __launch_bounds__(256, 3)
void knn_sim_topk(const float* __restrict__ q, const float* __restrict__ tx,
                  const float* __restrict__ rnorm,
                  float* __restrict__ pvals, int* __restrict__ pidx) {
  // LDS: As[32][68] + Bs[32][68] staged slices; S[64][68] sim tile aliases both;
  // merge phase (segment end) reuses the whole 40KB block.
  __shared__ float lds[10240];
  float* As = lds;                 // 32*68 = 2176 floats
  float* Bs = lds + 32 * LSTR;     // 2176 floats
  float* S  = lds;                 // 64*68 = 4352 floats (alias As+Bs)

  int t   = threadIdx.x;
  int tx_ = t & 15;                // micro-tile col group (n)
  int ty  = t >> 4;                // micro-tile row group (q)
  int qt  = blockIdx.x & 15;
  int seg = blockIdx.x >> 4;
  int qbase = qt * 64;
  int nseg0 = seg * SEGN;

  // register-resident top-20 (static indexing only — rule #20)
  float tvv[KTOP]; int tii[KTOP];
  #pragma unroll
  for (int i = 0; i < KTOP; ++i) { tvv[i] = -INFINITY; tii[i] = 0; }
  float tmin = -INFINITY;

  int qi_s = t >> 2, l_s = t & 3;  // scan-phase mapping: 4 lanes per query

  const float4* qv4 = reinterpret_cast<const float4*>(q);
  const float4* tx4 = reinterpret_cast<const float4*>(tx);

  for (int tile = 0; tile < TILES_PER_SEG; ++tile) {
    int nbase = nseg0 + tile * 64;

    float acc[4][4];
    #pragma unroll
    for (int i = 0; i < 4; ++i)
      #pragma unroll
      for (int j = 0; j < 4; ++j) acc[i][j] = 0.f;

    for (int ks = 0; ks < 8; ++ks) {
      __syncthreads();                       // protect LDS from previous phase
      // stage A (q slice) and B (train slice), transposed to [k][row]
      #pragma unroll
      for (int r = 0; r < 2; ++r) {
        int f = t + r * 256;
        int row = f >> 3, c4 = f & 7;        // row 0..63, c4 0..7 (float4 within 32-k slice)
        float4 av = qv4[(qbase + row) * 64 + ks * 8 + c4];
        int cb = c4 * 4;
        As[(cb + 0) * LSTR + row] = av.x;
        As[(cb + 1) * LSTR + row] = av.y;
        As[(cb + 2) * LSTR + row] = av.z;
        As[(cb + 3) * LSTR + row] = av.w;
        int gn = nbase + row;
        float4 bv = make_float4(0.f, 0.f, 0.f, 0.f);
        if (gn < NTRAIN) bv = tx4[gn * 64 + ks * 8 + c4];
        Bs[(cb + 0) * LSTR + row] = bv.x;
        Bs[(cb + 1) * LSTR + row] = bv.y;
        Bs[(cb + 2) * LSTR + row] = bv.z;
        Bs[(cb + 3) * LSTR + row] = bv.w;
      }
      __syncthreads();
      // compute: 32 k-steps, 2x ds_read_b128 + 16 FMA each
      #pragma unroll
      for (int k = 0; k < 32; ++k) {
        float4 a = *reinterpret_cast<const float4*>(&As[k * LSTR + ty * 4]);
        float4 b = *reinterpret_cast<const float4*>(&Bs[k * LSTR + tx_ * 4]);
        acc[0][0] += a.x * b.x; acc[0][1] += a.x * b.y; acc[0][2] += a.x * b.z; acc[0][3] += a.x * b.w;
        acc[1][0] += a.y * b.x; acc[1][1] += a.y * b.y; acc[1][2] += a.y * b.z; acc[1][3] += a.y * b.w;
        acc[2][0] += a.z * b.x; acc[2][1] += a.z * b.y; acc[2][2] += a.z * b.z; acc[2][3] += a.z * b.w;
        acc[3][0] += a.w * b.x; acc[3][1] += a.w * b.y; acc[3][2] += a.w * b.z; acc[3][3] += a.w * b.w;
      }
    }
    __syncthreads();
    // apply train-row normalization, write sim tile to LDS
    float rn[4];
    #pragma unroll
    for (int j = 0; j < 4; ++j) {
      int gn = nbase + tx_ * 4 + j;
      rn[j] = (gn < NTRAIN) ? rnorm[gn] : 0.f;
    }
    #pragma unroll
    for (int i = 0; i < 4; ++i) {
      float4 sv = make_float4(acc[i][0] * rn[0], acc[i][1] * rn[1],
                              acc[i][2] * rn[2], acc[i][3] * rn[3]);
      *reinterpret_cast<float4*>(&S[(ty * 4 + i) * LSTR + tx_ * 4]) = sv;
    }
    __syncthreads();
    // scan: 4 lanes/query, lane l handles n ≡ l (mod 4), ascending n (tie rule: keep earlier/lower idx)
    #pragma unroll
    for (int jj = 0; jj < 16; ++jj) {
      int ni = l_s + jj * 4;
      int gn = nbase + ni;
      float v = S[qi_s * LSTR + ni];
      if (gn < NTRAIN && v > tmin) {
        bool done = false;
        #pragma unroll
        for (int i = 0; i < KTOP; ++i) {
          bool hit = (!done) && (tvv[i] == tmin);
          if (hit) { tvv[i] = v; tii[i] = gn; done = true; }
        }
        tmin = tvv[0];
        #pragma unroll
        for (int i = 1; i < KTOP; ++i) tmin = fminf(tmin, tvv[i]);
      }
    }
  }

  // segment end: merge the 4 lanes of each query -> per-(query,segment) top-20
  __syncthreads();
  float* MV = lds;                                   // 256*20 floats
  int*   MI = reinterpret_cast<int*>(lds + 5120);    // 256*20 ints
  #pragma unroll
  for (int i = 0; i < KTOP; ++i) { MV[t * KTOP + i] = tvv[i]; MI[t * KTOP + i] = tii[i]; }
  __syncthreads();
  if (l_s == 0) {
    #pragma unroll 1
    for (int l = 1; l < 4; ++l) {
      #pragma unroll 1
      for (int i = 0; i < KTOP; ++i) {
        float v = MV[(t + l) * KTOP + i];
        int  gn = MI[(t + l) * KTOP + i];
        if (v > tmin) {
          bool done = false;
          #pragma unroll
          for (int u = 0; u < KTOP; ++u) {
            bool hit = (!done) && (tvv[u] == tmin);
            if (hit) { tvv[u] = v; tii[u] = gn; done = true; }
          }
          tmin = tvv[0];
          #pragma unroll
          for (int u = 1; u < KTOP; ++u) tmin = fminf(tmin, tvv[u]);
        }
      }
    }
    int qglob = qbase + qi_s;
    int base = (qglob * NSEG + seg) * KTOP;
    #pragma unroll
    for (int i = 0; i < KTOP; ++i) { pvals[base + i] = tvv[i]; pidx[base + i] = tii[i]; }
  }
}

// ---------------------------------------------------------------------------
// Kernel 4: per-query merge of 48*20 candidates -> exact top-20 (value desc,
// index asc tie-break = jax.lax.top_k), softmax(*20), scatter-add by label
// ---------------------------------------------------------------------------
#define NCAND (NSEG * KTOP)   // 960
__global__ void final_merge(const float* __restrict__ pvals, const int* __restrict__ pidx,
                            const int* __restrict__ train_y, float* __restrict__ out) {
  __shared__ float cv[NCAND];
  __shared__ int   ci[NCAND];
  __shared__ float wv[KTOP];
  __shared__ int   wi[KTOP];
  int b = blockIdx.x, lane = threadIdx.x;   // 64 threads = 1 wave
  for (int j = lane; j < NCAND; j += 64) { cv[j] = pvals[b * NCAND + j]; ci[j] = pidx[b * NCAND + j]; }
  __syncthreads();
  for (int it = 0; it < KTOP; ++it) {
    float bv = -INFINITY; int bi = 0x7fffffff; int bp = 0;
    for (int j = lane; j < NCAND; j += 64) {
      float v = cv[j]; int ii = ci[j];
      if (v > bv || (v == bv && ii < bi)) { bv = v; bi = ii; bp = j; }
    }
    #pragma unroll
    for (int off = 32; off; off >>= 1) {
      float ov = __shfl_xor(bv, off);
      int   oi = __shfl_xor(bi, off);
      int   op = __shfl_xor(bp, off);
      if (ov > bv || (ov == bv && oi < bi)) { bv = ov; bi = oi; bp = op; }
    }
    if (lane == 0) { wv[it] = bv; wi[it] = bi; cv[bp] = -INFINITY; }
    __syncthreads();
  }
  float e = 0.f;
  if (lane < KTOP) e = expf((wv[lane] - wv[0]) * TEMPF);
  float s = e;
  #pragma unroll
  for (int off = 32; off; off >>= 1) s += __shfl_xor(s, off);
  if (lane < KTOP) {
    float w = e / s;
    int label = train_y[wi[lane]];
    atomicAdd(&out[b * CCLS + label], w);
  }
}

// ---------------------------------------------------------------------------
extern "C" void kernel_launch(void* const* d_in, const int* in_sizes, int n_in,
                              void* d_out, int out_size, void* d_ws, size_t ws_size,
                              hipStream_t stream) {
  const float* x       = (const float*)d_in[0];
  const float* mean    = (const float*)d_in[1];
  const float* inv_std = (const float*)d_in[2];
  const float* train_x = (const float*)d_in[3];
  const int*   train_y = (const int*)d_in[4];
  float* out = (float*)d_out;

  // workspace carve (~9.7 MB total)
  char* w = (char*)d_ws;
  float* q     = (float*)w;  w += (size_t)BQ * D * 4;           // 1.05 MB
  float* rnorm = (float*)w;  w += (size_t)NTRAIN * 4;           // 0.80 MB
  float* pvals = (float*)w;  w += (size_t)BQ * NSEG * KTOP * 4; // 3.93 MB
  int*   pidx  = (int*)w;                                       // 3.93 MB

  hipMemsetAsync(d_out, 0, (size_t)BQ * CCLS * sizeof(float), stream);
  prep_q<<<BQ, 256, 0, stream>>>(x, mean, inv_std, q);
  row_norms<<<NTRAIN / 4, 256, 0, stream>>>(train_x, rnorm);
  knn_sim_topk<<<16 * NSEG, 256, 0, stream>>>(q, train_x, rnorm, pvals, pidx);
  final_merge<<<BQ, 64, 0, stream>>>(pvals, pidx, train_y, out);
}

// Round 2
// 1459.025 us; speedup vs baseline: 1.7786x; 1.7786x over previous
//
#include <hip/hip_runtime.h>
#include <math.h>

// Problem constants
#define BQ     1024
#define D      256
#define NTRAIN 200000
#define CCLS   1000
#define KTOP   20
#define KC     24          // candidate oversample per query
#define TEMPF  20.0f
#define EPSV   1e-8f

// GEMM tiling
#define NSEG    64         // segments over train set
#define SEGROWS 3125       // 64*3125 = 200000 exactly (disjoint)
#define SEGT    49         // ceil(3125/64) tiles of 64 rows
#define QT      128        // queries per block
#define SSTR    68         // LDS sim-tile stride (floats)

typedef __attribute__((ext_vector_type(8))) short bf16x8;  // 8 bf16 = 4 VGPR
typedef __attribute__((ext_vector_type(4))) float f32x4;

static __device__ __forceinline__ unsigned short f2bf(float f) {
  unsigned int u = __float_as_uint(f);
  u += 0x7FFFu + ((u >> 16) & 1u);     // RTNE
  return (unsigned short)(u >> 16);
}

// ---------------------------------------------------------------------------
// Kernel 1: qf = l2_normalize((x - mean) * inv_std)  (fp32) ; qb = bf16(qf)
// ---------------------------------------------------------------------------
__global__ void prep_q(const float* __restrict__ x, const float* __restrict__ mean,
                       const float* __restrict__ inv_std,
                       float* __restrict__ qf, unsigned short* __restrict__ qb) {
  int row = blockIdx.x;
  int t = threadIdx.x;                       // 256 threads, one element each
  float v = (x[row * D + t] - mean[t]) * inv_std[t];
  float s = v * v;
  #pragma unroll
  for (int off = 32; off; off >>= 1) s += __shfl_down(s, off);
  __shared__ float red[4];
  if ((t & 63) == 0) red[t >> 6] = s;
  __syncthreads();
  float tot = red[0] + red[1] + red[2] + red[3];
  float scale = 1.0f / fmaxf(sqrtf(tot), EPSV);
  float qv = v * scale;
  qf[row * D + t] = qv;
  qb[row * D + t] = f2bf(qv);
}

// ---------------------------------------------------------------------------
// Kernel 2: txb[n][k] = bf16(train_x[n][k] * rnorm[n]); rnorm[n] saved (fp32)
// one wave per row (4 rows / 256-thread block)
// ---------------------------------------------------------------------------
__global__ void bank_prep(const float* __restrict__ tx,
                          unsigned short* __restrict__ txb, float* __restrict__ rnorm) {
  int lane = threadIdx.x & 63;
  int row = blockIdx.x * 4 + (threadIdx.x >> 6);    // grid 50000 -> exact cover
  const float4* p = reinterpret_cast<const float4*>(tx + (size_t)row * D);
  float4 a = p[lane];
  float s = a.x * a.x + a.y * a.y + a.z * a.z + a.w * a.w;
  #pragma unroll
  for (int off = 32; off; off >>= 1) s += __shfl_xor(s, off);   // all lanes get sum
  float rn = 1.0f / fmaxf(sqrtf(s), EPSV);
  if (lane == 0) rnorm[row] = rn;
  ushort4 us;
  us.x = f2bf(a.x * rn); us.y = f2bf(a.y * rn);
  us.z = f2bf(a.z * rn); us.w = f2bf(a.w * rn);
  *reinterpret_cast<ushort4*>(txb + (size_t)row * D + lane * 4) = us;
}

// ---------------------------------------------------------------------------
// Kernel 3: bf16 MFMA sim GEMM + fused per-(query,segment) top-24
// grid 512 = 8 q-tiles x 64 segments; block 256 thr = 4 waves, wave owns 32 q.
// A (queries) register-resident; B (train rows) direct-from-global (L1/L2).
// ---------------------------------------------------------------------------
__global__ __launch_bounds__(256, 2)
void knn_mfma(const unsigned short* __restrict__ qb, const unsigned short* __restrict__ txb,
              float* __restrict__ pvals, int* __restrict__ pidx) {
  __shared__ float S[QT * SSTR];            // 34,816 B sim tile (reused for merge)

  int t = threadIdx.x;
  int lane = t & 63;
  int w = t >> 6;
  int c = lane & 15, g = lane >> 4;

  // segment-grouping swizzle: the 8 q-tiles of one segment land on one XCD
  int b = blockIdx.x;
  int seg = (b & 7) * 8 + ((b >> 3) & 7);
  int qt  = b >> 6;
  int qbase = qt * QT;
  int wq = qbase + w * 32;                  // wave's first query row

  // A fragments: af[mf][ks], lane holds A[row=wq+mf*16+c][k=ks*32+g*8 .. +7]
  bf16x8 af[2][8];
  #pragma unroll
  for (int mf = 0; mf < 2; ++mf)
    #pragma unroll
    for (int ks = 0; ks < 8; ++ks)
      af[mf][ks] = *reinterpret_cast<const bf16x8*>(
          qb + (size_t)(wq + mf * 16 + c) * D + ks * 32 + g * 8);

  // register top-24 (static indexing only)
  float tvv[KC]; int tii[KC];
  #pragma unroll
  for (int i = 0; i < KC; ++i) { tvv[i] = -INFINITY; tii[i] = 0; }
  float tmin = -INFINITY;

  auto insert24 = [&](float v, int gi) {
    bool done = false;
    #pragma unroll
    for (int i = 0; i < KC; ++i) {
      bool hit = (!done) && (tvv[i] == tmin);
      if (hit) { tvv[i] = v; tii[i] = gi; done = true; }
    }
    tmin = tvv[0];
    #pragma unroll
    for (int i = 1; i < KC; ++i) tmin = fminf(tmin, tvv[i]);
  };

  int nseg0 = seg * SEGROWS;
  int nsegEnd = nseg0 + SEGROWS;
  int q = t >> 1, pp = t & 1;               // scan mapping: 2 threads / query

  for (int tile = 0; tile < SEGT; ++tile) {
    int nbase = nseg0 + tile * 64;

    f32x4 acc[2][4];
    #pragma unroll
    for (int mf = 0; mf < 2; ++mf)
      #pragma unroll
      for (int nf = 0; nf < 4; ++nf) acc[mf][nf] = (f32x4){0.f, 0.f, 0.f, 0.f};

    #pragma unroll
    for (int ks = 0; ks < 8; ++ks) {
      bf16x8 bfr[4];
      #pragma unroll
      for (int nf = 0; nf < 4; ++nf) {
        int row = nbase + nf * 16 + c;
        row = (row < NTRAIN) ? row : (NTRAIN - 1);   // clamp (masked in scan)
        bfr[nf] = *reinterpret_cast<const bf16x8*>(
            txb + (size_t)row * D + ks * 32 + g * 8);
      }
      #pragma unroll
      for (int nf = 0; nf < 4; ++nf) {
        acc[0][nf] = __builtin_amdgcn_mfma_f32_16x16x32_bf16(af[0][ks], bfr[nf], acc[0][nf], 0, 0, 0);
        acc[1][nf] = __builtin_amdgcn_mfma_f32_16x16x32_bf16(af[1][ks], bfr[nf], acc[1][nf], 0, 0, 0);
      }
    }

    __syncthreads();                         // previous tile's scan done
    // C/D layout (m89): col = lane&15, row = (lane>>4)*4 + reg
    #pragma unroll
    for (int mf = 0; mf < 2; ++mf)
      #pragma unroll
      for (int nf = 0; nf < 4; ++nf)
        #pragma unroll
        for (int r = 0; r < 4; ++r)
          S[(w * 32 + mf * 16 + g * 4 + r) * SSTR + nf * 16 + c] = acc[mf][nf][r];
    __syncthreads();

    // scan: thread (q, pp) reads its 32 sims as 8 x b128
    #pragma unroll 1
    for (int jj = 0; jj < 8; ++jj) {
      f32x4 v4 = *reinterpret_cast<const f32x4*>(&S[q * SSTR + pp * 32 + jj * 4]);
      int g0 = nbase + pp * 32 + jj * 4;
      #pragma unroll
      for (int e = 0; e < 4; ++e) {
        if (g0 + e < nsegEnd && v4[e] > tmin) insert24(v4[e], g0 + e);
      }
    }
  }

  // merge the 2 threads of each query -> per-(q,seg) top-24
  __syncthreads();
  float* MV = S;                                   // [128][24]
  int*   MI = reinterpret_cast<int*>(S + QT * KC); // [128][24]
  if (pp == 1) {
    #pragma unroll
    for (int i = 0; i < KC; ++i) { MV[q * KC + i] = tvv[i]; MI[q * KC + i] = tii[i]; }
  }
  __syncthreads();
  if (pp == 0) {
    #pragma unroll 1
    for (int i = 0; i < KC; ++i) {
      float v = MV[q * KC + i]; int gi = MI[q * KC + i];
      if (v > tmin) insert24(v, gi);
    }
    int base = ((qbase + q) * NSEG + seg) * KC;
    #pragma unroll
    for (int i = 0; i < KC; ++i) { pvals[base + i] = tvv[i]; pidx[base + i] = tii[i]; }
  }
}

// ---------------------------------------------------------------------------
// Kernel 4: per query: top-24 of 64*24 bf16-sims -> exact fp32 rescore ->
// top-20 (value desc, idx asc) -> softmax(*20) -> scatter into out row
// block = 256 thr (4 waves) per query
// ---------------------------------------------------------------------------
#define NCAND (NSEG * KC)    // 1536
__global__ void final_sel(const float* __restrict__ pvals, const int* __restrict__ pidx,
                          const float* __restrict__ qf, const float* __restrict__ tx,
                          const float* __restrict__ rnorm, const int* __restrict__ train_y,
                          float* __restrict__ out) {
  __shared__ float cv[NCAND];
  __shared__ int   ci[NCAND];
  __shared__ float qs[D];
  __shared__ float wvv[4 * KC];
  __shared__ int   wii[4 * KC];
  __shared__ float selv[KC];
  __shared__ int   seli[KC];
  __shared__ float rsc[KC];
  __shared__ float ordv[KTOP];
  __shared__ int   ordi[KTOP];
  __shared__ float outrow[CCLS];

  int bq = blockIdx.x;
  int t = threadIdx.x, lane = t & 63, w = t >> 6;

  for (int j = t; j < CCLS; j += 256) outrow[j] = 0.f;
  qs[t] = qf[bq * D + t];
  #pragma unroll
  for (int i = 0; i < 6; ++i) {
    int j = i * 256 + t;
    cv[j] = pvals[(size_t)bq * NCAND + j];
    ci[j] = pidx[(size_t)bq * NCAND + j];
  }
  __syncthreads();

  // phase 1: per-wave top-24 over its 384 candidates
  float lv[6]; int li[6];
  #pragma unroll
  for (int i = 0; i < 6; ++i) { int j = w * 384 + i * 64 + lane; lv[i] = cv[j]; li[i] = ci[j]; }
  for (int it = 0; it < KC; ++it) {
    float bv = -INFINITY; int bi = 0x7fffffff;
    #pragma unroll
    for (int i = 0; i < 6; ++i)
      if (lv[i] > bv || (lv[i] == bv && li[i] < bi)) { bv = lv[i]; bi = li[i]; }
    #pragma unroll
    for (int off = 32; off; off >>= 1) {
      float ov = __shfl_xor(bv, off); int oi = __shfl_xor(bi, off);
      if (ov > bv || (ov == bv && oi < bi)) { bv = ov; bi = oi; }
    }
    #pragma unroll
    for (int i = 0; i < 6; ++i)
      if (li[i] == bi && lv[i] == bv) lv[i] = -INFINITY;
    if (lane == 0) { wvv[w * KC + it] = bv; wii[w * KC + it] = bi; }
  }
  __syncthreads();

  // phase 2: wave 0 merges 4x24 = 96 -> global top-24 candidates
  if (w == 0) {
    float m0 = wvv[lane]; int i0 = wii[lane];
    float m1 = (lane < 32) ? wvv[64 + lane] : -INFINITY;
    int   i1 = (lane < 32) ? wii[64 + lane] : 0x7fffffff;
    for (int it = 0; it < KC; ++it) {
      float bv = m0; int bi = i0;
      if (m1 > bv || (m1 == bv && i1 < bi)) { bv = m1; bi = i1; }
      #pragma unroll
      for (int off = 32; off; off >>= 1) {
        float ov = __shfl_xor(bv, off); int oi = __shfl_xor(bi, off);
        if (ov > bv || (ov == bv && oi < bi)) { bv = ov; bi = oi; }
      }
      if (i0 == bi && m0 == bv) m0 = -INFINITY;
      if (i1 == bi && m1 == bv) m1 = -INFINITY;
      if (lane == 0) { selv[it] = bv; seli[it] = bi; }
    }
  }
  __syncthreads();

  // phase 3: exact fp32 rescore of the 24 candidates (wave w does k = w, w+4, ...)
  for (int k = w; k < KC; k += 4) {
    int idx = seli[k];
    float4 tv = reinterpret_cast<const float4*>(tx + (size_t)idx * D)[lane];
    float4 qv = *reinterpret_cast<const float4*>(&qs[lane * 4]);
    float s = tv.x * qv.x + tv.y * qv.y + tv.z * qv.z + tv.w * qv.w;
    #pragma unroll
    for (int off = 32; off; off >>= 1) s += __shfl_xor(s, off);
    if (lane == 0) rsc[k] = s * rnorm[idx];
  }
  __syncthreads();

  // phase 4: wave 0: top-20 of 24 (value desc, idx asc), softmax, scatter
  if (w == 0) {
    float v = (lane < KC) ? rsc[lane] : -INFINITY;
    int   i = (lane < KC) ? seli[lane] : 0x7fffffff;
    for (int it = 0; it < KTOP; ++it) {
      float bv = v; int bi = i;
      #pragma unroll
      for (int off = 32; off; off >>= 1) {
        float ov = __shfl_xor(bv, off); int oi = __shfl_xor(bi, off);
        if (ov > bv || (ov == bv && oi < bi)) { bv = ov; bi = oi; }
      }
      if (v == bv && i == bi) v = -INFINITY;
      if (lane == 0) { ordv[it] = bv; ordi[it] = bi; }
    }
    float e = (lane < KTOP) ? expf((ordv[lane] - ordv[0]) * TEMPF) : 0.f;
    float ssum = e;
    #pragma unroll
    for (int off = 32; off; off >>= 1) ssum += __shfl_xor(ssum, off);
    if (lane < KTOP) {
      int label = train_y[ordi[lane]];
      atomicAdd(&outrow[label], e / ssum);
    }
  }
  __syncthreads();
  // write full output row (no global memset needed)
  if (t < 250) reinterpret_cast<float4*>(out)[bq * 250 + t] =
      reinterpret_cast<const float4*>(outrow)[t];
}

// ---------------------------------------------------------------------------
extern "C" void kernel_launch(void* const* d_in, const int* in_sizes, int n_in,
                              void* d_out, int out_size, void* d_ws, size_t ws_size,
                              hipStream_t stream) {
  const float* x       = (const float*)d_in[0];
  const float* mean    = (const float*)d_in[1];
  const float* inv_std = (const float*)d_in[2];
  const float* train_x = (const float*)d_in[3];
  const int*   train_y = (const int*)d_in[4];
  float* out = (float*)d_out;

  // workspace carve (~117.3 MB)
  char* wp = (char*)d_ws;
  float*          qf    = (float*)wp;          wp += (size_t)BQ * D * 4;            // 1.0 MB
  unsigned short* qb    = (unsigned short*)wp; wp += (size_t)BQ * D * 2;            // 0.5 MB
  float*          rnorm = (float*)wp;          wp += (size_t)NTRAIN * 4;            // 0.8 MB
  unsigned short* txb   = (unsigned short*)wp; wp += (size_t)NTRAIN * D * 2;        // 102.4 MB
  float*          pvals = (float*)wp;          wp += (size_t)BQ * NSEG * KC * 4;    // 6.3 MB
  int*            pidx  = (int*)wp;                                                 // 6.3 MB

  prep_q   <<<BQ, 256, 0, stream>>>(x, mean, inv_std, qf, qb);
  bank_prep<<<NTRAIN / 4, 256, 0, stream>>>(train_x, txb, rnorm);
  knn_mfma <<<8 * NSEG, 256, 0, stream>>>(qb, txb, pvals, pidx);
  final_sel<<<BQ, 256, 0, stream>>>(pvals, pidx, qf, train_x, rnorm, train_y, out);
}